// Round 2
// baseline (11658.960 us; speedup 1.0000x reference)
//
#include <hip/hip_runtime.h>
#include <hip/hip_bf16.h>
#include <hip/hip_fp16.h>

// GRU scan, B=128 T=1024 D=256 H=256. ALL I/O IS FLOAT32 (per reference).
// Kernel 1: xp = obs @ Wi + bi  -> d_ws as f16 [131072, 768]
//           (fp32 inputs converted to f16 in staging; mfma_f32_16x16x32_f16)
// Kernel 2: persistent per-batch-element GRU scan, weights f16-packed in VGPRs,
//           v_dot2_f32_f16 matvecs, h broadcast via LDS, 1 barrier/step.

#define B_ 128
#define T_ 1024
#define D_ 256
#define H_ 256

typedef _Float16 half2v __attribute__((ext_vector_type(2)));
typedef _Float16 half8v __attribute__((ext_vector_type(8)));
typedef float f32x4 __attribute__((ext_vector_type(4)));

__device__ __forceinline__ float dot2f(half2v a, half2v b, float c) {
  return __builtin_amdgcn_fdot2(a, b, c, false);
}

// ---------------- Kernel 1: xp = obs @ Wi + bi ----------------
__global__ __launch_bounds__(256, 2) void xproj_gemm(
    const float* __restrict__ A,    // obs [131072, 256] fp32
    const float* __restrict__ W,    // Wi  [256, 768] fp32
    const float* __restrict__ bias, // bi  [768] fp32
    _Float16* __restrict__ C)       // xp  [131072, 768] f16
{
  constexpr int LDS_K = 40;  // 32 + 8 pad
  __shared__ __align__(16) _Float16 As[128 * LDS_K];   // [m][k]
  __shared__ __align__(16) _Float16 Bs[128 * LDS_K];   // [n][k] (transposed)
  const int m0 = blockIdx.x * 128;
  const int n0 = blockIdx.y * 128;
  const int tid = threadIdx.x;
  const int lane = tid & 63;
  const int wv = tid >> 6;
  const int wm = (wv >> 1) * 64;   // wave's 64x64 quadrant
  const int wn = (wv & 1) * 64;
  const int q = lane >> 4;
  const int lm = lane & 15;

  f32x4 acc[4][4];
#pragma unroll
  for (int i = 0; i < 4; ++i)
#pragma unroll
    for (int j = 0; j < 4; ++j)
      acc[i][j] = (f32x4){0.f, 0.f, 0.f, 0.f};

  const int ar = tid >> 1, ac = (tid & 1) * 16;   // A stage: row, 16-col chunk
  const int bk = tid >> 3, bj = (tid & 7) * 16;   // B stage: k-row, 16-col chunk

  for (int k0 = 0; k0 < 256; k0 += 32) {
    // stage A tile 128x32: thread loads 16 fp32, converts to f16
    const float* ap = A + (size_t)(m0 + ar) * 256 + k0 + ac;
    float4 a0 = *(const float4*)(ap + 0);
    float4 a1 = *(const float4*)(ap + 4);
    float4 a2 = *(const float4*)(ap + 8);
    float4 a3 = *(const float4*)(ap + 12);
    // stage B tile 32x128 (row bk, cols bj..bj+15), transposed into [n][k]
    const float* bp = W + (size_t)(k0 + bk) * 768 + n0 + bj;
    float4 b0 = *(const float4*)(bp + 0);
    float4 b1 = *(const float4*)(bp + 4);
    float4 b2 = *(const float4*)(bp + 8);
    float4 b3 = *(const float4*)(bp + 12);

    _Float16 av[16];
    av[0] = (_Float16)a0.x; av[1] = (_Float16)a0.y; av[2] = (_Float16)a0.z; av[3] = (_Float16)a0.w;
    av[4] = (_Float16)a1.x; av[5] = (_Float16)a1.y; av[6] = (_Float16)a1.z; av[7] = (_Float16)a1.w;
    av[8] = (_Float16)a2.x; av[9] = (_Float16)a2.y; av[10] = (_Float16)a2.z; av[11] = (_Float16)a2.w;
    av[12] = (_Float16)a3.x; av[13] = (_Float16)a3.y; av[14] = (_Float16)a3.z; av[15] = (_Float16)a3.w;
    *(int4*)&As[ar * LDS_K + ac] = *(int4*)&av[0];
    *(int4*)&As[ar * LDS_K + ac + 8] = *(int4*)&av[8];

    _Float16 bvv[16];
    bvv[0] = (_Float16)b0.x; bvv[1] = (_Float16)b0.y; bvv[2] = (_Float16)b0.z; bvv[3] = (_Float16)b0.w;
    bvv[4] = (_Float16)b1.x; bvv[5] = (_Float16)b1.y; bvv[6] = (_Float16)b1.z; bvv[7] = (_Float16)b1.w;
    bvv[8] = (_Float16)b2.x; bvv[9] = (_Float16)b2.y; bvv[10] = (_Float16)b2.z; bvv[11] = (_Float16)b2.w;
    bvv[12] = (_Float16)b3.x; bvv[13] = (_Float16)b3.y; bvv[14] = (_Float16)b3.z; bvv[15] = (_Float16)b3.w;
#pragma unroll
    for (int i = 0; i < 16; ++i) Bs[(bj + i) * LDS_K + bk] = bvv[i];
    __syncthreads();

    half8v af[4], bfr[4];
#pragma unroll
    for (int i = 0; i < 4; ++i)
      af[i] = *(const half8v*)&As[(wm + i * 16 + lm) * LDS_K + q * 8];
#pragma unroll
    for (int j = 0; j < 4; ++j)
      bfr[j] = *(const half8v*)&Bs[(wn + j * 16 + lm) * LDS_K + q * 8];
#pragma unroll
    for (int i = 0; i < 4; ++i)
#pragma unroll
      for (int j = 0; j < 4; ++j)
        acc[i][j] = __builtin_amdgcn_mfma_f32_16x16x32_f16(af[i], bfr[j], acc[i][j], 0, 0, 0);
    __syncthreads();
  }

  // epilogue: C/D layout col = lane&15, row = (lane>>4)*4 + reg
#pragma unroll
  for (int j = 0; j < 4; ++j) {
    const int n = n0 + wn + j * 16 + lm;
    const float bv = bias[n];
#pragma unroll
    for (int i = 0; i < 4; ++i) {
#pragma unroll
      for (int r = 0; r < 4; ++r) {
        const int m = m0 + wm + i * 16 + q * 4 + r;
        C[(size_t)m * 768 + n] = (_Float16)(acc[i][j][r] + bv);
      }
    }
  }
}

// ---------------- Kernel 2: GRU scan ----------------
// 128 blocks (one per batch element), 256 threads, 1 wave/SIMD.
// Thread t owns output cols: r[t] (Wh_rz col t), z[t] (col 256+t), n[t] (Wh_n col t).
__global__ __launch_bounds__(256, 1) void gru_scan(
    const _Float16* __restrict__ xp,  // [B*T, 768] f16
    const int* __restrict__ done,     // [B, T] int32
    const float* __restrict__ h0,     // [B, H] fp32
    const float* __restrict__ Wh_rz,  // [H, 2H] fp32
    const float* __restrict__ Wh_n,   // [H, H] fp32
    const float* __restrict__ bh_n,   // [H] fp32
    float* __restrict__ out_final,    // [B, H] fp32
    float* __restrict__ out_ys)       // [B, T, H] fp32
{
  const int b = blockIdx.x;
  const int tid = threadIdx.x;
  __shared__ __align__(16) _Float16 h_lds[2][H_];

  // one-time: this thread's weight columns -> f16 pairs in VGPRs (384 regs)
  half2v wr[H_ / 2], wz[H_ / 2], wn[H_ / 2];
#pragma unroll 8
  for (int p = 0; p < H_ / 2; ++p) {
    wr[p] = (half2v){(_Float16)Wh_rz[(size_t)(2 * p) * 512 + tid],
                     (_Float16)Wh_rz[(size_t)(2 * p + 1) * 512 + tid]};
    wz[p] = (half2v){(_Float16)Wh_rz[(size_t)(2 * p) * 512 + 256 + tid],
                     (_Float16)Wh_rz[(size_t)(2 * p + 1) * 512 + 256 + tid]};
    wn[p] = (half2v){(_Float16)Wh_n[(size_t)(2 * p) * 256 + tid],
                     (_Float16)Wh_n[(size_t)(2 * p + 1) * 256 + tid]};
  }
  const float bhn = bh_n[tid];
  float h_cur = h0[b * H_ + tid];

  const _Float16* xpb = xp + (size_t)b * T_ * 768;
  const int* dnb = done + (size_t)b * T_;
  int dcur = dnb[0];

  for (int t = 0; t < T_; ++t) {
    const float hm = dcur ? 0.f : h_cur;           // reset-on-done (pre-step)
    h_lds[t & 1][tid] = (_Float16)hm;
    __syncthreads();
    // deferred ys store for previous step (keeps stores off the barrier drain)
    if (t > 0)
      out_ys[((size_t)b * T_ + (t - 1)) * H_ + tid] = h_cur;
    // loads for THIS step, issued right after the barrier (hide under dots)
    const size_t xo = (size_t)t * 768 + tid;
    float xr = (float)xpb[xo];
    float xz = (float)xpb[xo + 256];
    float xn = (float)xpb[xo + 512];
    dcur = dnb[t + 1 < T_ ? t + 1 : t];            // prefetch next done

    const half8v* h8p = (const half8v*)h_lds[t & 1];
    float ra = 0.f, rb = 0.f, za = 0.f, zb = 0.f, na = 0.f, nb = 0.f;
#pragma unroll
    for (int c = 0; c < 32; ++c) {
      half8v h8 = h8p[c];
#pragma unroll
      for (int i = 0; i < 4; ++i) {
        half2v hv = {h8[2 * i], h8[2 * i + 1]};
        const int p = c * 4 + i;
        if (i & 1) {
          rb = dot2f(hv, wr[p], rb);
          zb = dot2f(hv, wz[p], zb);
          nb = dot2f(hv, wn[p], nb);
        } else {
          ra = dot2f(hv, wr[p], ra);
          za = dot2f(hv, wz[p], za);
          na = dot2f(hv, wn[p], na);
        }
      }
    }
    const float rsum = xr + ra + rb;
    const float zsum = xz + za + zb;
    const float r = 1.f / (1.f + __expf(-rsum));
    const float z = 1.f / (1.f + __expf(-zsum));
    const float npre = xn + r * ((na + nb) + bhn);
    const float e = __expf(-2.f * fabsf(npre));    // saturating tanh
    const float tv = (1.f - e) / (1.f + e);
    const float n = npre < 0.f ? -tv : tv;
    h_cur = (1.f - z) * n + z * hm;
  }
  out_ys[((size_t)b * T_ + (T_ - 1)) * H_ + tid] = h_cur;
  out_final[b * H_ + tid] = h_cur;
}

extern "C" void kernel_launch(void* const* d_in, const int* in_sizes, int n_in,
                              void* d_out, int out_size, void* d_ws, size_t ws_size,
                              hipStream_t stream) {
  const float* obs   = (const float*)d_in[0];
  const int*   done  = (const int*)d_in[1];
  const float* h0    = (const float*)d_in[2];
  const float* Wi    = (const float*)d_in[3];
  const float* bi    = (const float*)d_in[4];
  const float* Wh_rz = (const float*)d_in[5];
  const float* Wh_n  = (const float*)d_in[6];
  const float* bh_n  = (const float*)d_in[7];
  float* out = (float*)d_out;                 // [final_h (B*H) | ys (B*T*H)]
  _Float16* xp = (_Float16*)d_ws;             // [131072, 768] f16 (201 MB)

  xproj_gemm<<<dim3(1024, 6), 256, 0, stream>>>(obs, Wi, bi, xp);
  gru_scan<<<dim3(128), 256, 0, stream>>>(xp, done, h0, Wh_rz, Wh_n, bh_n,
                                          out, out + B_ * H_);
}

// Round 3
// 3928.036 us; speedup vs baseline: 2.9681x; 2.9681x over previous
//
#include <hip/hip_runtime.h>
#include <hip/hip_bf16.h>
#include <hip/hip_fp16.h>

// GRU scan, B=128 T=1024 D=256 H=256. ALL I/O IS FLOAT32 (per reference).
// Kernel 1: xp = obs @ Wi + bi  -> d_ws as f16 [131072, 768]
// Kernel 2: persistent per-batch-element GRU scan, weights f16-packed in VGPRs,
//           v_dot2_f32_f16 matvecs, h broadcast via LDS, 1 barrier/step.
//
// R2 lesson: weight-load loop MUST be fully unrolled — `#pragma unroll 8`
// left non-constant array indices, LLVM couldn't SROA wr/wz/wn, the whole
// 384-VGPR weight set went to scratch (VGPR_Count=36, 25 GB HBM/dispatch,
// VALUBusy 3.5%). Full unroll => constant indices => registers.

#define B_ 128
#define T_ 1024
#define D_ 256
#define H_ 256

typedef _Float16 half2v __attribute__((ext_vector_type(2)));
typedef _Float16 half8v __attribute__((ext_vector_type(8)));
typedef float f32x4 __attribute__((ext_vector_type(4)));

__device__ __forceinline__ float dot2f(half2v a, half2v b, float c) {
  return __builtin_amdgcn_fdot2(a, b, c, false);
}

// ---------------- Kernel 1: xp = obs @ Wi + bi ----------------
__global__ __launch_bounds__(256, 2) void xproj_gemm(
    const float* __restrict__ A,    // obs [131072, 256] fp32
    const float* __restrict__ W,    // Wi  [256, 768] fp32
    const float* __restrict__ bias, // bi  [768] fp32
    _Float16* __restrict__ C)       // xp  [131072, 768] f16
{
  constexpr int LDS_K = 40;  // 32 + 8 pad
  __shared__ __align__(16) _Float16 As[128 * LDS_K];   // [m][k]
  __shared__ __align__(16) _Float16 Bs[128 * LDS_K];   // [n][k] (transposed)
  const int m0 = blockIdx.x * 128;
  const int n0 = blockIdx.y * 128;
  const int tid = threadIdx.x;
  const int lane = tid & 63;
  const int wv = tid >> 6;
  const int wm = (wv >> 1) * 64;   // wave's 64x64 quadrant
  const int wn = (wv & 1) * 64;
  const int q = lane >> 4;
  const int lm = lane & 15;

  f32x4 acc[4][4];
#pragma unroll
  for (int i = 0; i < 4; ++i)
#pragma unroll
    for (int j = 0; j < 4; ++j)
      acc[i][j] = (f32x4){0.f, 0.f, 0.f, 0.f};

  const int ar = tid >> 1, ac = (tid & 1) * 16;   // A stage: row, 16-col chunk
  const int bk = tid >> 3, bj = (tid & 7) * 16;   // B stage: k-row, 16-col chunk

  for (int k0 = 0; k0 < 256; k0 += 32) {
    const float* ap = A + (size_t)(m0 + ar) * 256 + k0 + ac;
    float4 a0 = *(const float4*)(ap + 0);
    float4 a1 = *(const float4*)(ap + 4);
    float4 a2 = *(const float4*)(ap + 8);
    float4 a3 = *(const float4*)(ap + 12);
    const float* bp = W + (size_t)(k0 + bk) * 768 + n0 + bj;
    float4 b0 = *(const float4*)(bp + 0);
    float4 b1 = *(const float4*)(bp + 4);
    float4 b2 = *(const float4*)(bp + 8);
    float4 b3 = *(const float4*)(bp + 12);

    _Float16 av[16];
    av[0] = (_Float16)a0.x; av[1] = (_Float16)a0.y; av[2] = (_Float16)a0.z; av[3] = (_Float16)a0.w;
    av[4] = (_Float16)a1.x; av[5] = (_Float16)a1.y; av[6] = (_Float16)a1.z; av[7] = (_Float16)a1.w;
    av[8] = (_Float16)a2.x; av[9] = (_Float16)a2.y; av[10] = (_Float16)a2.z; av[11] = (_Float16)a2.w;
    av[12] = (_Float16)a3.x; av[13] = (_Float16)a3.y; av[14] = (_Float16)a3.z; av[15] = (_Float16)a3.w;
    *(int4*)&As[ar * LDS_K + ac] = *(int4*)&av[0];
    *(int4*)&As[ar * LDS_K + ac + 8] = *(int4*)&av[8];

    _Float16 bvv[16];
    bvv[0] = (_Float16)b0.x; bvv[1] = (_Float16)b0.y; bvv[2] = (_Float16)b0.z; bvv[3] = (_Float16)b0.w;
    bvv[4] = (_Float16)b1.x; bvv[5] = (_Float16)b1.y; bvv[6] = (_Float16)b1.z; bvv[7] = (_Float16)b1.w;
    bvv[8] = (_Float16)b2.x; bvv[9] = (_Float16)b2.y; bvv[10] = (_Float16)b2.z; bvv[11] = (_Float16)b2.w;
    bvv[12] = (_Float16)b3.x; bvv[13] = (_Float16)b3.y; bvv[14] = (_Float16)b3.z; bvv[15] = (_Float16)b3.w;
#pragma unroll
    for (int i = 0; i < 16; ++i) Bs[(bj + i) * LDS_K + bk] = bvv[i];
    __syncthreads();

    half8v af[4], bfr[4];
#pragma unroll
    for (int i = 0; i < 4; ++i)
      af[i] = *(const half8v*)&As[(wm + i * 16 + lm) * LDS_K + q * 8];
#pragma unroll
    for (int j = 0; j < 4; ++j)
      bfr[j] = *(const half8v*)&Bs[(wn + j * 16 + lm) * LDS_K + q * 8];
#pragma unroll
    for (int i = 0; i < 4; ++i)
#pragma unroll
      for (int j = 0; j < 4; ++j)
        acc[i][j] = __builtin_amdgcn_mfma_f32_16x16x32_f16(af[i], bfr[j], acc[i][j], 0, 0, 0);
    __syncthreads();
  }

  // epilogue: C/D layout col = lane&15, row = (lane>>4)*4 + reg
#pragma unroll
  for (int j = 0; j < 4; ++j) {
    const int n = n0 + wn + j * 16 + lm;
    const float bv = bias[n];
#pragma unroll
    for (int i = 0; i < 4; ++i) {
#pragma unroll
      for (int r = 0; r < 4; ++r) {
        const int m = m0 + wm + i * 16 + q * 4 + r;
        C[(size_t)m * 768 + n] = (_Float16)(acc[i][j][r] + bv);
      }
    }
  }
}

// ---------------- Kernel 2: GRU scan ----------------
// 128 blocks (one per batch element), 256 threads, 1 wave/SIMD.
// Thread t owns output cols: r[t] (Wh_rz col t), z[t] (col 256+t), n[t] (Wh_n col t).
__global__ __launch_bounds__(256, 1) void gru_scan(
    const _Float16* __restrict__ xp,  // [B*T, 768] f16
    const int* __restrict__ done,     // [B, T] int32
    const float* __restrict__ h0,     // [B, H] fp32
    const float* __restrict__ Wh_rz,  // [H, 2H] fp32
    const float* __restrict__ Wh_n,   // [H, H] fp32
    const float* __restrict__ bh_n,   // [H] fp32
    float* __restrict__ out_final,    // [B, H] fp32
    float* __restrict__ out_ys)       // [B, T, H] fp32
{
  const int b = blockIdx.x;
  const int tid = threadIdx.x;
  __shared__ __align__(16) _Float16 h_lds[2][H_];

  // one-time: this thread's weight columns -> f16 pairs in VGPRs (384 regs).
  // FULL unroll is mandatory: constant indices => SROA => registers (R2 bug).
  half2v wr[H_ / 2], wz[H_ / 2], wn[H_ / 2];
#pragma unroll
  for (int p = 0; p < H_ / 2; ++p) {
    wr[p] = (half2v){(_Float16)Wh_rz[(size_t)(2 * p) * 512 + tid],
                     (_Float16)Wh_rz[(size_t)(2 * p + 1) * 512 + tid]};
    wz[p] = (half2v){(_Float16)Wh_rz[(size_t)(2 * p) * 512 + 256 + tid],
                     (_Float16)Wh_rz[(size_t)(2 * p + 1) * 512 + 256 + tid]};
    wn[p] = (half2v){(_Float16)Wh_n[(size_t)(2 * p) * 256 + tid],
                     (_Float16)Wh_n[(size_t)(2 * p + 1) * 256 + tid]};
  }
  const float bhn = bh_n[tid];
  float h_cur = h0[b * H_ + tid];

  const _Float16* xpb = xp + (size_t)b * T_ * 768;
  const int* dnb = done + (size_t)b * T_;
  int dcur = dnb[0];

  for (int t = 0; t < T_; ++t) {
    const float hm = dcur ? 0.f : h_cur;           // reset-on-done (pre-step)
    h_lds[t & 1][tid] = (_Float16)hm;
    __syncthreads();
    // deferred ys store for previous step (keeps stores off the barrier drain)
    if (t > 0)
      out_ys[((size_t)b * T_ + (t - 1)) * H_ + tid] = h_cur;
    // loads for THIS step, issued right after the barrier (hide under dots)
    const size_t xo = (size_t)t * 768 + tid;
    float xr = (float)xpb[xo];
    float xz = (float)xpb[xo + 256];
    float xn = (float)xpb[xo + 512];
    dcur = dnb[t + 1 < T_ ? t + 1 : t];            // prefetch next done

    const half8v* h8p = (const half8v*)h_lds[t & 1];
    float ra = 0.f, rb = 0.f, za = 0.f, zb = 0.f, na = 0.f, nb = 0.f;
#pragma unroll
    for (int c = 0; c < 32; ++c) {
      half8v h8 = h8p[c];
#pragma unroll
      for (int i = 0; i < 4; ++i) {
        half2v hv = {h8[2 * i], h8[2 * i + 1]};
        const int p = c * 4 + i;
        if (i & 1) {
          rb = dot2f(hv, wr[p], rb);
          zb = dot2f(hv, wz[p], zb);
          nb = dot2f(hv, wn[p], nb);
        } else {
          ra = dot2f(hv, wr[p], ra);
          za = dot2f(hv, wz[p], za);
          na = dot2f(hv, wn[p], na);
        }
      }
    }
    const float rsum = xr + ra + rb;
    const float zsum = xz + za + zb;
    const float r = 1.f / (1.f + __expf(-rsum));
    const float z = 1.f / (1.f + __expf(-zsum));
    const float npre = xn + r * ((na + nb) + bhn);
    const float e = __expf(-2.f * fabsf(npre));    // saturating tanh
    const float tv = (1.f - e) / (1.f + e);
    const float n = npre < 0.f ? -tv : tv;
    h_cur = (1.f - z) * n + z * hm;
  }
  out_ys[((size_t)b * T_ + (T_ - 1)) * H_ + tid] = h_cur;
  out_final[b * H_ + tid] = h_cur;
}

extern "C" void kernel_launch(void* const* d_in, const int* in_sizes, int n_in,
                              void* d_out, int out_size, void* d_ws, size_t ws_size,
                              hipStream_t stream) {
  const float* obs   = (const float*)d_in[0];
  const int*   done  = (const int*)d_in[1];
  const float* h0    = (const float*)d_in[2];
  const float* Wi    = (const float*)d_in[3];
  const float* bi    = (const float*)d_in[4];
  const float* Wh_rz = (const float*)d_in[5];
  const float* Wh_n  = (const float*)d_in[6];
  const float* bh_n  = (const float*)d_in[7];
  float* out = (float*)d_out;                 // [final_h (B*H) | ys (B*T*H)]
  _Float16* xp = (_Float16*)d_ws;             // [131072, 768] f16 (201 MB)

  xproj_gemm<<<dim3(1024, 6), 256, 0, stream>>>(obs, Wi, bi, xp);
  gru_scan<<<dim3(128), 256, 0, stream>>>(xp, done, h0, Wh_rz, Wh_n, bh_n,
                                          out, out + B_ * H_);
}